// Round 11
// baseline (304.785 us; speedup 1.0000x reference)
//
#include <hip/hip_runtime.h>

#define B 8
#define N 1024
#define M 128
#define KF 16
#define C 16
#define DPE 64
#define NE 131072
#define NV (B*N)
#define NM (N*M)
#define BN_EPS 1e-5f

typedef short bf16x8 __attribute__((ext_vector_type(8)));
typedef float f32x4 __attribute__((ext_vector_type(4)));

__device__ inline unsigned short f2bf_rne(float f) {
    unsigned u = __float_as_uint(f);
    u += 0x7fffu + ((u >> 16) & 1u);
    return (unsigned short)(u >> 16);
}
__device__ inline float bf2f(unsigned short s) {
    return __uint_as_float((unsigned)s << 16);
}
__device__ inline void split_bf16(float v, unsigned short& hi, unsigned short& lo) {
    hi = f2bf_rne(v);
    float hf = __uint_as_float((unsigned)hi << 16);
    lo = f2bf_rne(v - hf);
}
union U4 { uint4 v; unsigned short s[8]; };
union U2 { uint2 v; unsigned short s[4]; };

// Pf frag-major (uint4 units) per buffer: PF4(b,msub,ks,hl,l)
// frag el: m = 16*msub + (l&15), kcol = 32*ks + 8*(l>>4) + j
__device__ __host__ inline size_t PF4(int b, int msub, int ks, int hl, int l) {
    return ((((size_t)b * 8 + msub) * 32 + ks) * 2 + hl) * 64 + l;
}
#define PFBUF ((size_t)B * 8 * 32 * 2 * 64)   // uint4 per Pf buffer (4MB)

// ---------- fused prep: W plane0 + W-frags (merged, one W read) | edge hist ----------
__global__ __launch_bounds__(256) void prep_all(const float* __restrict__ W,
                                                const int* __restrict__ ei,
                                                uint4* __restrict__ Pf,
                                                unsigned short* __restrict__ feat,
                                                int* __restrict__ cnt) {
    __shared__ float T[32][33];
    int blk = blockIdx.x;
    int t = threadIdx.x;
    if (blk < 1024) {                         // ---- plane0 + frags ----
        int b = blk & 7;
        int tile = blk >> 3;
        int nt = tile & 31, mt = tile >> 5;
        int n0 = nt * 32, m0 = mt * 32;
        {
            int nl = t >> 3, mq = t & 7;
            float4 v = *(const float4*)(W + ((size_t)b * N + n0 + nl) * M + m0 + mq * 4);
            T[nl][mq * 4 + 0] = v.x; T[nl][mq * 4 + 1] = v.y;
            T[nl][mq * 4 + 2] = v.z; T[nl][mq * 4 + 3] = v.w;
        }
        __syncthreads();
        {   // plane 0 (bf16, [m][node])
            int ml = t >> 3, nq = t & 7;
            U2 o;
            o.s[0] = f2bf_rne(T[nq * 4 + 0][ml]);
            o.s[1] = f2bf_rne(T[nq * 4 + 1][ml]);
            o.s[2] = f2bf_rne(T[nq * 4 + 2][ml]);
            o.s[3] = f2bf_rne(T[nq * 4 + 3][ml]);
            unsigned short* plane = feat + (size_t)b * KF * NM;  // plane 0
            *(uint2*)(plane + (size_t)(m0 + ml) * N + n0 + nq * 4) = o.v;
        }
        if (t < 128) {  // frags for (ks=nt, msub=2mt+unit) from T
            int unit = t >> 6, l = t & 63;
            int msub = 2 * mt + unit;
            U4 hi, lo;
            #pragma unroll
            for (int j = 0; j < 8; j++) {
                float v = T[8 * (l >> 4) + j][16 * unit + (l & 15)];
                split_bf16(v, hi.s[j], lo.s[j]);
            }
            Pf[PF4(b, msub, nt, 0, l)] = hi.v;
            Pf[PF4(b, msub, nt, 1, l)] = lo.v;
        }
    } else {                                  // ---- edge_hist ----
        int e = (blk - 1024) * 256 + t;
        bool is64 = (ei[1] == 0 && ei[3] == 0 && ei[5] == 0 && ei[7] == 0);
        int dst = is64 ? ei[2 * (NE + e)] : ei[NE + e];
        atomicAdd(&cnt[dst], 1);
    }
}

// ---------- persistent MFMA chain (R28-exact; best known) ----------
__global__ __launch_bounds__(512) void gemm_chain(const float* __restrict__ Lap,
                                                  uint4* __restrict__ PfA,
                                                  uint4* __restrict__ PfB,
                                                  unsigned short* __restrict__ feat,
                                                  unsigned* bar) {
    extern __shared__ __align__(16) char smem[];
    uint4* ldsS = (uint4*)smem;               // 8192 uint4 = 128 KB
    float* Dl = (float*)(smem + 131072);      // 128 x 36 floats = 18.4 KB

    int b = blockIdx.x & 7, bx = blockIdx.x >> 3;   // XCD pinning
    int t = threadIdx.x;
    int w = t >> 6, lane = t & 63;
    int g = w >> 2, wq = w & 3;               // K-half, msub-pair
    int n0 = 32 * bx;

    // startup: S slice direct from Lap -> LDS, conflict-free mapping (R27)
    {
        int nl = (lane & 15) + 16 * (t >> 8);
        int kg = (lane >> 4) + 4 * ((t >> 6) & 3);
        const float* row = Lap + ((size_t)b * N + n0 + nl) * N;
        int base = (t >> 8) * 4096;
        #pragma unroll
        for (int jj = 0; jj < 8; jj++) {
            int koct = kg + 16 * jj;
            int k0 = koct * 8;
            float4 f0 = *(const float4*)(row + k0);
            float4 f1 = *(const float4*)(row + k0 + 4);
            float e[8] = {f0.x, f0.y, f0.z, f0.w, f1.x, f1.y, f1.z, f1.w};
            U4 hi, lo;
            #pragma unroll
            for (int j = 0; j < 8; j++) split_bf16(e[j], hi.s[j], lo.s[j]);
            int ks = koct >> 2;
            int l = (nl & 15) + 16 * (koct & 3);     // == lane
            ldsS[base + ks * 128 + l] = hi.v;
            ldsS[base + ks * 128 + 64 + l] = lo.v;
        }
    }
    __syncthreads();

    #pragma unroll 1
    for (int k = 0; k < KF - 1; k++) {
        const uint4* PfIn = (k & 1) ? PfB : PfA;
        uint4* PfOut      = (k & 1) ? PfA : PfB;
        const uint4* Pw0 = PfIn + (size_t)(b * 8 + 2 * wq) * 4096 + (size_t)(16 * g) * 128;
        const uint4* Pw1 = Pw0 + 4096;

        f32x4 acc[2][2] = {};                 // [mi][ni]
        uint4 ph[2][2], pl[2][2];             // [ring][mi]
        #pragma unroll
        for (int q = 0; q < 2; q++) {
            ph[q][0] = Pw0[(size_t)q * 128 + lane];
            pl[q][0] = Pw0[(size_t)q * 128 + 64 + lane];
            ph[q][1] = Pw1[(size_t)q * 128 + lane];
            pl[q][1] = Pw1[(size_t)q * 128 + 64 + lane];
        }
        #pragma unroll 2
        for (int ks = 0; ks < 16; ks++) {
            int kg = 16 * g + ks;
            uint4 a0h = ph[ks & 1][0], a0l = pl[ks & 1][0];
            uint4 a1h = ph[ks & 1][1], a1l = pl[ks & 1][1];
            if (ks < 14) {
                ph[ks & 1][0] = Pw0[(size_t)(ks + 2) * 128 + lane];
                pl[ks & 1][0] = Pw0[(size_t)(ks + 2) * 128 + 64 + lane];
                ph[ks & 1][1] = Pw1[(size_t)(ks + 2) * 128 + lane];
                pl[ks & 1][1] = Pw1[(size_t)(ks + 2) * 128 + 64 + lane];
            }
            bf16x8 b0h = __builtin_bit_cast(bf16x8, ldsS[kg * 128 + lane]);
            bf16x8 b0l = __builtin_bit_cast(bf16x8, ldsS[kg * 128 + 64 + lane]);
            bf16x8 b1h = __builtin_bit_cast(bf16x8, ldsS[4096 + kg * 128 + lane]);
            bf16x8 b1l = __builtin_bit_cast(bf16x8, ldsS[4096 + kg * 128 + 64 + lane]);
            bf16x8 A0h = __builtin_bit_cast(bf16x8, a0h);
            bf16x8 A0l = __builtin_bit_cast(bf16x8, a0l);
            bf16x8 A1h = __builtin_bit_cast(bf16x8, a1h);
            bf16x8 A1l = __builtin_bit_cast(bf16x8, a1l);
            acc[0][0] = __builtin_amdgcn_mfma_f32_16x16x32_bf16(A0h, b0h, acc[0][0], 0, 0, 0);
            acc[0][0] = __builtin_amdgcn_mfma_f32_16x16x32_bf16(A0h, b0l, acc[0][0], 0, 0, 0);
            acc[0][0] = __builtin_amdgcn_mfma_f32_16x16x32_bf16(A0l, b0h, acc[0][0], 0, 0, 0);
            acc[0][1] = __builtin_amdgcn_mfma_f32_16x16x32_bf16(A0h, b1h, acc[0][1], 0, 0, 0);
            acc[0][1] = __builtin_amdgcn_mfma_f32_16x16x32_bf16(A0h, b1l, acc[0][1], 0, 0, 0);
            acc[0][1] = __builtin_amdgcn_mfma_f32_16x16x32_bf16(A0l, b1h, acc[0][1], 0, 0, 0);
            acc[1][0] = __builtin_amdgcn_mfma_f32_16x16x32_bf16(A1h, b0h, acc[1][0], 0, 0, 0);
            acc[1][0] = __builtin_amdgcn_mfma_f32_16x16x32_bf16(A1h, b0l, acc[1][0], 0, 0, 0);
            acc[1][0] = __builtin_amdgcn_mfma_f32_16x16x32_bf16(A1l, b0h, acc[1][0], 0, 0, 0);
            acc[1][1] = __builtin_amdgcn_mfma_f32_16x16x32_bf16(A1h, b1h, acc[1][1], 0, 0, 0);
            acc[1][1] = __builtin_amdgcn_mfma_f32_16x16x32_bf16(A1h, b1l, acc[1][1], 0, 0, 0);
            acc[1][1] = __builtin_amdgcn_mfma_f32_16x16x32_bf16(A1l, b1h, acc[1][1], 0, 0, 0);
        }

        // ---- K-half reduction through Dl: g=1 writes, g=0 adds ----
        if (g == 1) {
            #pragma unroll
            for (int mi = 0; mi < 2; mi++)
                #pragma unroll
                for (int ni = 0; ni < 2; ni++)
                    #pragma unroll
                    for (int r = 0; r < 4; r++) {
                        int m = 32 * wq + 16 * mi + 4 * (lane >> 4) + r;
                        int c = 16 * ni + (lane & 15);
                        Dl[m * 36 + c] = acc[mi][ni][r];
                    }
        }
        __syncthreads();
        if (g == 0) {
            #pragma unroll
            for (int mi = 0; mi < 2; mi++)
                #pragma unroll
                for (int ni = 0; ni < 2; ni++)
                    #pragma unroll
                    for (int r = 0; r < 4; r++) {
                        int m = 32 * wq + 16 * mi + 4 * (lane >> 4) + r;
                        int c = 16 * ni + (lane & 15);
                        Dl[m * 36 + c] += acc[mi][ni][r];
                    }
        }
        __syncthreads();

        // ---- merged conversion: ONE split pass -> feat plane + Pf frags ----
        {
            int m = t >> 2, c0 = (t & 3) * 8;
            float4 v0 = *(const float4*)&Dl[m * 36 + c0];
            float4 v1 = *(const float4*)&Dl[m * 36 + c0 + 4];
            float e[8] = {v0.x, v0.y, v0.z, v0.w, v1.x, v1.y, v1.z, v1.w};
            U4 hi, lo;
            #pragma unroll
            for (int j = 0; j < 8; j++) split_bf16(e[j], hi.s[j], lo.s[j]);
            unsigned short* plane = feat + ((size_t)b * KF + (k + 1)) * NM
                                        + (size_t)m * N + n0 + c0;
            *(uint4*)plane = hi.v;
            if (k < KF - 2) {
                int l = (m & 15) + 16 * (c0 >> 3);
                PfOut[PF4(b, m >> 4, bx, 0, l)] = hi.v;
                PfOut[PF4(b, m >> 4, bx, 1, l)] = lo.v;
            }
        }
        if (k < KF - 2) {
            __syncthreads();   // drains all waves' stores to L2 (vmcnt 0)
            if (t == 0) {
                __hip_atomic_fetch_add(&bar[b * 32], 1u, __ATOMIC_RELAXED,
                                       __HIP_MEMORY_SCOPE_AGENT);
                unsigned target = 32u * (unsigned)(k + 1);
                while (__hip_atomic_load(&bar[b * 32], __ATOMIC_RELAXED,
                                         __HIP_MEMORY_SCOPE_AGENT) < target)
                    __builtin_amdgcn_s_sleep(1);
            }
            __syncthreads();
            asm volatile("buffer_inv sc0\n\ts_waitcnt vmcnt(0)" ::: "memory");
        }
    }
}

// ---------- fused BN: stats + per-batch barrier + apply, ONE feat read ----------
// R29: blocks 0..255 = (batch b = blk&7, node-slice n0 = (blk>>3)*32).
// feat slice [16][128][32] bf16 cached in LDS (k-stride 4112 ushorts, padded);
// stats from LDS -> atomicAdd -> t0-spin barrier (target 32, bar[256+b*32])
// -> buffer_inv -> apply BN+relu+mean-over-M from the SAME LDS slice.
// Replaces bn_stats (full feat read) + bn_x (full feat read, stride-2KB
// scalar loads). Block 256 = edge CSR scan.
#define KSTR 4112
__global__ __launch_bounds__(512) void bn_fused(const unsigned short* __restrict__ feat,
                                                const float* __restrict__ lin_w,
                                                const float* __restrict__ lin_b,
                                                const float* __restrict__ gam,
                                                const float* __restrict__ bet,
                                                float* __restrict__ stats,
                                                unsigned* bar,
                                                float* __restrict__ x,
                                                const int* __restrict__ cnt,
                                                int* __restrict__ off,
                                                int* __restrict__ cur) {
    extern __shared__ __align__(16) char smem2[];
    unsigned short* fs = (unsigned short*)smem2;   // 16 x 4112 ushort = 131584 B
    float* red = (float*)(smem2 + 131584);         // 8 x 544 floats = 17408 B
    __shared__ float wls[KF * C];
    __shared__ int ss[256];
    int t = threadIdx.x;

    if (blockIdx.x >= 256) {              // ---- edge_scan (block 256) ----
        int s = 0;
        int local[32];
        int base = t * 32;
        if (t < 256) {
            #pragma unroll
            for (int i = 0; i < 32; i++) { local[i] = cnt[base + i]; s += local[i]; }
            ss[t] = s;
        }
        __syncthreads();
        #pragma unroll
        for (int d = 1; d < 256; d <<= 1) {
            int v = (t >= d && t < 256) ? ss[t - d] : 0;
            __syncthreads();
            if (t < 256) ss[t] += v;
            __syncthreads();
        }
        if (t < 256) {
            int excl = ss[t] - s;
            #pragma unroll
            for (int i = 0; i < 32; i++) { off[base + i] = excl; cur[base + i] = excl; excl += local[i]; }
        }
        return;
    }

    int b = blockIdx.x & 7, n0 = (blockIdx.x >> 3) * 32;
    if (t < KF * C) wls[t] = lin_w[t];

    // ---- load feat slice -> LDS (coalesced; 16 uint4 per thread) ----
    uint4* fsu = (uint4*)fs;
    #pragma unroll
    for (int i = 0; i < 16; i++) {
        int idx = t + 512 * i;
        int k = idx >> 9, r = idx & 511;
        int m = r >> 2, c = r & 3;
        const uint4* src = (const uint4*)(feat + ((size_t)b * KF + k) * NM
                                               + (size_t)m * N + n0);
        fsu[k * (KSTR / 8) + m * 4 + c] = src[c];
    }
    __syncthreads();

    // ---- stats: each thread covers 8 elements (wave-contiguous e = t+512j) ----
    float bb[C];
    #pragma unroll
    for (int c = 0; c < C; c++) bb[c] = lin_b[c];
    float s[C] = {}, ssq[C] = {};
    #pragma unroll
    for (int j = 0; j < 8; j++) {
        int e = t + 512 * j;
        float p[KF];
        #pragma unroll
        for (int kk = 0; kk < KF; kk++) p[kk] = bf2f(fs[kk * KSTR + e]);
        #pragma unroll
        for (int c = 0; c < C; c++) {
            float h = bb[c];
            #pragma unroll
            for (int kk = 0; kk < KF; kk++) h = fmaf(p[kk], wls[kk * C + c], h);
            s[c] += h;
            ssq[c] = fmaf(h, h, ssq[c]);
        }
    }
    #pragma unroll
    for (int o = 32; o > 0; o >>= 1)
        #pragma unroll
        for (int c = 0; c < C; c++) {
            s[c] += __shfl_down(s[c], o);
            ssq[c] += __shfl_down(ssq[c], o);
        }
    int w = t >> 6;
    if ((t & 63) == 0) {
        #pragma unroll
        for (int c = 0; c < C; c++) { red[w * 32 + c] = s[c]; red[256 + w * 32 + c] = ssq[c]; }
    }
    __syncthreads();
    if (t < 32) {
        int which = t >> 4, c = t & 15;
        float v = 0.0f;
        #pragma unroll
        for (int wv = 0; wv < 8; wv++) v += red[which * 256 + wv * 32 + c];
        atomicAdd(&stats[b * 32 + which * 16 + c], v);
    }
    __syncthreads();   // drains the atomics (each wave waits vmcnt before barrier)

    // ---- per-batch barrier: all 32 blocks' stats landed ----
    if (t == 0) {
        __hip_atomic_fetch_add(&bar[256 + b * 32], 1u, __ATOMIC_RELAXED,
                               __HIP_MEMORY_SCOPE_AGENT);
        while (__hip_atomic_load(&bar[256 + b * 32], __ATOMIC_RELAXED,
                                 __HIP_MEMORY_SCOPE_AGENT) < 32u)
            __builtin_amdgcn_s_sleep(1);
    }
    __syncthreads();
    asm volatile("buffer_inv sc0\n\ts_waitcnt vmcnt(0)" ::: "memory");

    // ---- apply: BN + relu + mean over M from the SAME LDS slice ----
    const float inv_nm = 1.0f / (float)NM;
    float sc[C], sh[C];
    #pragma unroll
    for (int c = 0; c < C; c++) {
        float mean = stats[b * 32 + c] * inv_nm;
        float var = stats[b * 32 + 16 + c] * inv_nm - mean * mean;
        sc[c] = gam[c] * rsqrtf(var + BN_EPS);
        sh[c] = bet[c] - mean * sc[c];
    }
    int nl = t & 31, mg = t >> 5;             // 16 m-groups x 8 m each
    float y[C] = {};
    #pragma unroll
    for (int mi = 0; mi < 8; mi++) {
        int m = mg * 8 + mi;
        float p[KF];
        #pragma unroll
        for (int kk = 0; kk < KF; kk++) p[kk] = bf2f(fs[kk * KSTR + m * 32 + nl]);
        #pragma unroll
        for (int c = 0; c < C; c++) {
            float h = bb[c];
            #pragma unroll
            for (int kk = 0; kk < KF; kk++) h = fmaf(p[kk], wls[kk * C + c], h);
            y[c] += fmaxf(fmaf(h, sc[c], sh[c]), 0.0f);
        }
    }
    if (mg < 8) {
        #pragma unroll
        for (int c = 0; c < C; c++) red[mg * 544 + nl * 17 + c] = y[c];
    }
    __syncthreads();
    if (mg >= 8) {
        #pragma unroll
        for (int c = 0; c < C; c++) red[(mg - 8) * 544 + nl * 17 + c] += y[c];
    }
    __syncthreads();
    {
        int snl = t >> 4, c = t & 15;
        float v = 0.0f;
        #pragma unroll
        for (int m8 = 0; m8 < 8; m8++) v += red[m8 * 544 + snl * 17 + c];
        x[((size_t)b * N + n0 + snl) * C + c] = v * (1.0f / (float)M);
    }
}

// ---------- edge fill (standalone) ----------
__global__ __launch_bounds__(256) void edge_fill(const int* __restrict__ ei,
                                                 int* __restrict__ cur,
                                                 int* __restrict__ bucket) {
    int e = blockIdx.x * 256 + threadIdx.x;
    bool is64 = (ei[1] == 0 && ei[3] == 0 && ei[5] == 0 && ei[7] == 0);
    int src, dst;
    if (is64) { src = ei[2 * e]; dst = ei[2 * (NE + e)]; }
    else      { src = ei[e];     dst = ei[NE + e]; }
    int pos = atomicAdd(&cur[dst], 1);
    bucket[pos] = src;
}

// ---------- fused gather + phi1 + phi2 ----------
__global__ __launch_bounds__(256) void phi_fused(const int* __restrict__ cnt,
                                                 const int* __restrict__ off,
                                                 const int* __restrict__ bucket,
                                                 const float* __restrict__ x,
                                                 const float* __restrict__ w1,
                                                 const float* __restrict__ b1,
                                                 const float* __restrict__ w2,
                                                 const float* __restrict__ b2,
                                                 float* __restrict__ out) {
    __shared__ float w1s[C * DPE];
    __shared__ float w2s[DPE * DPE];
    __shared__ float b2s[DPE];
    __shared__ float gsh[16][17];
    __shared__ float h1sh[16][DPE];
    int t = threadIdx.x;
    #pragma unroll
    for (int q = 0; q < 4; q++) w1s[t + q * 256] = w1[t + q * 256];
    #pragma unroll
    for (int q = 0; q < 16; q++) w2s[t + q * 256] = w2[t + q * 256];
    if (t < DPE) b2s[t] = b2[t];

    {   // gather: node nl, channel c
        int nl = t >> 4, c = t & 15;
        int n = blockIdx.x * 16 + nl;
        int o = off[n], d = cnt[n];
        float v = x[(size_t)n * C + c];
        int j = 0;
        for (; j + 4 <= d; j += 4) {
            int s0 = bucket[o + j], s1 = bucket[o + j + 1];
            int s2 = bucket[o + j + 2], s3 = bucket[o + j + 3];
            v += x[(size_t)s0 * C + c];
            v += x[(size_t)s1 * C + c];
            v += x[(size_t)s2 * C + c];
            v += x[(size_t)s3 * C + c];
        }
        for (; j < d; j++) v += x[(size_t)bucket[o + j] * C + c];
        gsh[nl][c] = v;
    }
    __syncthreads();
    #pragma unroll
    for (int q = 0; q < 4; q++) {       // phi1: 16 nodes x 64
        int item = t + 256 * q;
        int node = item >> 6, j = item & 63;
        float h = b1[j];
        #pragma unroll
        for (int c = 0; c < C; c++) h = fmaf(gsh[node][c], w1s[c * DPE + j], h);
        h1sh[node][j] = fmaxf(h, 0.0f);
    }
    __syncthreads();
    #pragma unroll
    for (int q = 0; q < 4; q++) {       // phi2: 16 nodes x 64
        int item = t + 256 * q;
        int node = item >> 6, d = item & 63;
        float o2 = b2s[d];
        #pragma unroll
        for (int j = 0; j < DPE; j++) o2 = fmaf(h1sh[node][j], w2s[j * DPE + d], o2);
        out[((size_t)blockIdx.x * 16 + node) * DPE + d] = o2;
    }
}

extern "C" void kernel_launch(void* const* d_in, const int* in_sizes, int n_in,
                              void* d_out, int out_size, void* d_ws, size_t ws_size,
                              hipStream_t stream) {
    const float* Lap   = (const float*)d_in[0];
    const float* W     = (const float*)d_in[1];
    const float* lin_w = (const float*)d_in[2];
    const float* lin_b = (const float*)d_in[3];
    const float* gam   = (const float*)d_in[4];
    const float* bet   = (const float*)d_in[5];
    const float* w1    = (const float*)d_in[6];
    const float* b1    = (const float*)d_in[7];
    const float* w2    = (const float*)d_in[8];
    const float* b2    = (const float*)d_in[9];
    const int*   ei    = (const int*)d_in[10];

    char* wsb = (char*)d_ws;
    unsigned short* feat = (unsigned short*)wsb;             // 32 MB (bf16)
    uint4* Pf    = (uint4*)(wsb + ((size_t)32 << 20));       // 8 MB (2 buffers)
    char* tail   = wsb + ((size_t)40 << 20);
    float* stats = (float*)tail;                             // 1 KB
    unsigned* bar = (unsigned*)(tail + 1024);                // gemm [0..255], bn [256..511]
    int* cnt     = (int*)(tail + 8192);                      // NV ints (32 KB)
    float* x     = (float*)(tail + 40960);
    int* off     = (int*)(x + (size_t)NV * C);
    int* cur     = off + NV;
    int* bucket  = cur + NV;                                 // NE ints
    float* out   = (float*)d_out;

    // allow >64KB dynamic LDS for the two big kernels; idempotent host-side
    static bool attr_set = false;
    if (!attr_set) {
        hipFuncSetAttribute((const void*)gemm_chain,
                            hipFuncAttributeMaxDynamicSharedMemorySize, 149504);
        hipFuncSetAttribute((const void*)bn_fused,
                            hipFuncAttributeMaxDynamicSharedMemorySize, 148992);
        attr_set = true;
    }

    // one memset covers stats + bar + cnt (contiguous 40 KB)
    hipMemsetAsync(tail, 0, 40960, stream);
    prep_all<<<dim3(1536), 256, 0, stream>>>(W, ei, Pf, feat, cnt);
    gemm_chain<<<dim3(256), 512, 149504, stream>>>(Lap, Pf, Pf + PFBUF, feat, bar);
    bn_fused<<<dim3(257), 512, 148992, stream>>>(feat, lin_w, lin_b, gam, bet,
                                                 stats, bar, x, cnt, off, cur);
    edge_fill<<<dim3(NE / 256), 256, 0, stream>>>(ei, cur, bucket);
    phi_fused<<<dim3(NV / 16), 256, 0, stream>>>(cnt, off, bucket, x, w1, b1, w2, b2, out);
}

// Round 12
// 275.222 us; speedup vs baseline: 1.1074x; 1.1074x over previous
//
#include <hip/hip_runtime.h>

#define B 8
#define N 1024
#define M 128
#define KF 16
#define C 16
#define DPE 64
#define NE 131072
#define NV (B*N)
#define NM (N*M)
#define BN_EPS 1e-5f

typedef short bf16x8 __attribute__((ext_vector_type(8)));
typedef float f32x4 __attribute__((ext_vector_type(4)));

__device__ inline unsigned short f2bf_rne(float f) {
    unsigned u = __float_as_uint(f);
    u += 0x7fffu + ((u >> 16) & 1u);
    return (unsigned short)(u >> 16);
}
__device__ inline float bf2f(unsigned short s) {
    return __uint_as_float((unsigned)s << 16);
}
__device__ inline void split_bf16(float v, unsigned short& hi, unsigned short& lo) {
    hi = f2bf_rne(v);
    float hf = __uint_as_float((unsigned)hi << 16);
    lo = f2bf_rne(v - hf);
}
union U4 { uint4 v; unsigned short s[8]; };
union U2 { uint2 v; unsigned short s[4]; };

// Pf frag-major (uint4 units) per buffer: PF4(b,msub,ks,hl,l)
// frag el: m = 16*msub + (l&15), kcol = 32*ks + 8*(l>>4) + j
__device__ __host__ inline size_t PF4(int b, int msub, int ks, int hl, int l) {
    return ((((size_t)b * 8 + msub) * 32 + ks) * 2 + hl) * 64 + l;
}
#define PFBUF ((size_t)B * 8 * 32 * 2 * 64)   // uint4 per Pf buffer (4MB)

// ---------- persistent MFMA chain with folded prep (R30) ----------
// R30: prep_all folded into gemm startup. Block (b,bx) produces its OWN
// Pf chunk ks=bx (W rows 32bx..32bx+31 staged coalesced into the idle Dl
// region, converted from LDS) + plane-0 slice + 512 edge-hist entries,
// using the proven t0-spin barrier (separate counter bar[256+b*32],
// target 32) before k=0 consumes PfA. Plane0 + edge-hist stores overlap
// the spin. K-loop and epilogue are R28-exact (best known, 142-145us).
// Pinned: LDS atomics bad (R26); one-spinner-per-block only (R19/R21);
// 32 blocks/batch + split-K topology unique optimum (R22-R24).
__global__ __launch_bounds__(512) void gemm_chain(const float* __restrict__ Lap,
                                                  const float* __restrict__ W,
                                                  const int* __restrict__ ei,
                                                  uint4* __restrict__ PfA,
                                                  uint4* __restrict__ PfB,
                                                  unsigned short* __restrict__ feat,
                                                  unsigned* bar,
                                                  int* __restrict__ cnt) {
    extern __shared__ __align__(16) char smem[];
    uint4* ldsS = (uint4*)smem;               // 8192 uint4 = 128 KB
    float* Dl = (float*)(smem + 131072);      // 128 x 36 floats = 18.4 KB

    int b = blockIdx.x & 7, bx = blockIdx.x >> 3;   // XCD pinning
    int t = threadIdx.x;
    int w = t >> 6, lane = t & 63;
    int g = w >> 2, wq = w & 3;               // K-half, msub-pair
    int n0 = 32 * bx;

    // ---- startup A: S slice Lap->ldsS (conflict-free, R27) + W rows->Dl ----
    {
        int nl = (lane & 15) + 16 * (t >> 8);
        int kg = (lane >> 4) + 4 * ((t >> 6) & 3);
        const float* row = Lap + ((size_t)b * N + n0 + nl) * N;
        int base = (t >> 8) * 4096;
        #pragma unroll
        for (int jj = 0; jj < 8; jj++) {
            int koct = kg + 16 * jj;
            int k0 = koct * 8;
            float4 f0 = *(const float4*)(row + k0);
            float4 f1 = *(const float4*)(row + k0 + 4);
            float e[8] = {f0.x, f0.y, f0.z, f0.w, f1.x, f1.y, f1.z, f1.w};
            U4 hi, lo;
            #pragma unroll
            for (int j = 0; j < 8; j++) split_bf16(e[j], hi.s[j], lo.s[j]);
            int ks = koct >> 2;
            int l = (nl & 15) + 16 * (koct & 3);     // == lane
            ldsS[base + ks * 128 + l] = hi.v;
            ldsS[base + ks * 128 + 64 + l] = lo.v;
        }
    }
    {   // W rows n0..n0+31 (all m) -> Dl, coalesced float4 (16 KB)
        const float4* wsrc = (const float4*)(W + ((size_t)b * N + n0) * M);
        float4* dl4 = (float4*)Dl;
        dl4[t] = wsrc[t];
        dl4[t + 512] = wsrc[t + 512];
    }
    __syncthreads();

    // ---- startup B: produce Pf chunk ks=bx from Dl; plane0 + edge hist
    //      overlap the init barrier spin ----
    {
        int msub = t >> 6, l = lane;              // (msub, l) covers chunk bx
        U4 hi, lo;
        #pragma unroll
        for (int j = 0; j < 8; j++) {
            float v = Dl[(8 * (l >> 4) + j) * 128 + 16 * msub + (l & 15)];
            split_bf16(v, hi.s[j], lo.s[j]);
        }
        PfA[PF4(b, msub, bx, 0, l)] = hi.v;
        PfA[PF4(b, msub, bx, 1, l)] = lo.v;
        __syncthreads();   // drains frag stores (vmcnt 0 per wave)
        if (t == 0)
            __hip_atomic_fetch_add(&bar[256 + b * 32], 1u, __ATOMIC_RELAXED,
                                   __HIP_MEMORY_SCOPE_AGENT);
        // plane 0 ([m][n] bf16) -- no intra-kernel consumer; overlaps spin
        {
            int m = 16 * msub + (l & 15);
            unsigned short* plane = feat + (size_t)b * KF * NM
                                        + (size_t)m * N + n0 + 8 * (l >> 4);
            *(uint4*)plane = hi.v;
        }
        {   // edge histogram: 512 edges per block
            int e = blockIdx.x * 512 + t;
            bool is64 = (ei[1] == 0 && ei[3] == 0 && ei[5] == 0 && ei[7] == 0);
            int dst = is64 ? ei[2 * (NE + e)] : ei[NE + e];
            atomicAdd(&cnt[dst], 1);
        }
        if (t == 0) {
            while (__hip_atomic_load(&bar[256 + b * 32], __ATOMIC_RELAXED,
                                     __HIP_MEMORY_SCOPE_AGENT) < 32u)
                __builtin_amdgcn_s_sleep(1);
        }
        __syncthreads();
        asm volatile("buffer_inv sc0\n\ts_waitcnt vmcnt(0)" ::: "memory");
    }

    #pragma unroll 1
    for (int k = 0; k < KF - 1; k++) {
        const uint4* PfIn = (k & 1) ? PfB : PfA;
        uint4* PfOut      = (k & 1) ? PfA : PfB;
        const uint4* Pw0 = PfIn + (size_t)(b * 8 + 2 * wq) * 4096 + (size_t)(16 * g) * 128;
        const uint4* Pw1 = Pw0 + 4096;

        f32x4 acc[2][2] = {};                 // [mi][ni]
        uint4 ph[2][2], pl[2][2];             // [ring][mi]
        #pragma unroll
        for (int q = 0; q < 2; q++) {
            ph[q][0] = Pw0[(size_t)q * 128 + lane];
            pl[q][0] = Pw0[(size_t)q * 128 + 64 + lane];
            ph[q][1] = Pw1[(size_t)q * 128 + lane];
            pl[q][1] = Pw1[(size_t)q * 128 + 64 + lane];
        }
        #pragma unroll 2
        for (int ks = 0; ks < 16; ks++) {
            int kg = 16 * g + ks;
            uint4 a0h = ph[ks & 1][0], a0l = pl[ks & 1][0];
            uint4 a1h = ph[ks & 1][1], a1l = pl[ks & 1][1];
            if (ks < 14) {
                ph[ks & 1][0] = Pw0[(size_t)(ks + 2) * 128 + lane];
                pl[ks & 1][0] = Pw0[(size_t)(ks + 2) * 128 + 64 + lane];
                ph[ks & 1][1] = Pw1[(size_t)(ks + 2) * 128 + lane];
                pl[ks & 1][1] = Pw1[(size_t)(ks + 2) * 128 + 64 + lane];
            }
            bf16x8 b0h = __builtin_bit_cast(bf16x8, ldsS[kg * 128 + lane]);
            bf16x8 b0l = __builtin_bit_cast(bf16x8, ldsS[kg * 128 + 64 + lane]);
            bf16x8 b1h = __builtin_bit_cast(bf16x8, ldsS[4096 + kg * 128 + lane]);
            bf16x8 b1l = __builtin_bit_cast(bf16x8, ldsS[4096 + kg * 128 + 64 + lane]);
            bf16x8 A0h = __builtin_bit_cast(bf16x8, a0h);
            bf16x8 A0l = __builtin_bit_cast(bf16x8, a0l);
            bf16x8 A1h = __builtin_bit_cast(bf16x8, a1h);
            bf16x8 A1l = __builtin_bit_cast(bf16x8, a1l);
            acc[0][0] = __builtin_amdgcn_mfma_f32_16x16x32_bf16(A0h, b0h, acc[0][0], 0, 0, 0);
            acc[0][0] = __builtin_amdgcn_mfma_f32_16x16x32_bf16(A0h, b0l, acc[0][0], 0, 0, 0);
            acc[0][0] = __builtin_amdgcn_mfma_f32_16x16x32_bf16(A0l, b0h, acc[0][0], 0, 0, 0);
            acc[0][1] = __builtin_amdgcn_mfma_f32_16x16x32_bf16(A0h, b1h, acc[0][1], 0, 0, 0);
            acc[0][1] = __builtin_amdgcn_mfma_f32_16x16x32_bf16(A0h, b1l, acc[0][1], 0, 0, 0);
            acc[0][1] = __builtin_amdgcn_mfma_f32_16x16x32_bf16(A0l, b1h, acc[0][1], 0, 0, 0);
            acc[1][0] = __builtin_amdgcn_mfma_f32_16x16x32_bf16(A1h, b0h, acc[1][0], 0, 0, 0);
            acc[1][0] = __builtin_amdgcn_mfma_f32_16x16x32_bf16(A1h, b0l, acc[1][0], 0, 0, 0);
            acc[1][0] = __builtin_amdgcn_mfma_f32_16x16x32_bf16(A1l, b0h, acc[1][0], 0, 0, 0);
            acc[1][1] = __builtin_amdgcn_mfma_f32_16x16x32_bf16(A1h, b1h, acc[1][1], 0, 0, 0);
            acc[1][1] = __builtin_amdgcn_mfma_f32_16x16x32_bf16(A1h, b1l, acc[1][1], 0, 0, 0);
            acc[1][1] = __builtin_amdgcn_mfma_f32_16x16x32_bf16(A1l, b1h, acc[1][1], 0, 0, 0);
        }

        // ---- K-half reduction through Dl: g=1 writes, g=0 adds ----
        if (g == 1) {
            #pragma unroll
            for (int mi = 0; mi < 2; mi++)
                #pragma unroll
                for (int ni = 0; ni < 2; ni++)
                    #pragma unroll
                    for (int r = 0; r < 4; r++) {
                        int m = 32 * wq + 16 * mi + 4 * (lane >> 4) + r;
                        int c = 16 * ni + (lane & 15);
                        Dl[m * 36 + c] = acc[mi][ni][r];
                    }
        }
        __syncthreads();
        if (g == 0) {
            #pragma unroll
            for (int mi = 0; mi < 2; mi++)
                #pragma unroll
                for (int ni = 0; ni < 2; ni++)
                    #pragma unroll
                    for (int r = 0; r < 4; r++) {
                        int m = 32 * wq + 16 * mi + 4 * (lane >> 4) + r;
                        int c = 16 * ni + (lane & 15);
                        Dl[m * 36 + c] += acc[mi][ni][r];
                    }
        }
        __syncthreads();

        // ---- merged conversion: ONE split pass -> feat plane + Pf frags ----
        {
            int m = t >> 2, c0 = (t & 3) * 8;
            float4 v0 = *(const float4*)&Dl[m * 36 + c0];
            float4 v1 = *(const float4*)&Dl[m * 36 + c0 + 4];
            float e[8] = {v0.x, v0.y, v0.z, v0.w, v1.x, v1.y, v1.z, v1.w};
            U4 hi, lo;
            #pragma unroll
            for (int j = 0; j < 8; j++) split_bf16(e[j], hi.s[j], lo.s[j]);
            unsigned short* plane = feat + ((size_t)b * KF + (k + 1)) * NM
                                        + (size_t)m * N + n0 + c0;
            *(uint4*)plane = hi.v;
            if (k < KF - 2) {
                int l = (m & 15) + 16 * (c0 >> 3);
                PfOut[PF4(b, m >> 4, bx, 0, l)] = hi.v;
                PfOut[PF4(b, m >> 4, bx, 1, l)] = lo.v;
            }
        }
        if (k < KF - 2) {
            __syncthreads();   // drains all waves' stores to L2 (vmcnt 0)
            if (t == 0) {
                __hip_atomic_fetch_add(&bar[b * 32], 1u, __ATOMIC_RELAXED,
                                       __HIP_MEMORY_SCOPE_AGENT);
                unsigned target = 32u * (unsigned)(k + 1);
                while (__hip_atomic_load(&bar[b * 32], __ATOMIC_RELAXED,
                                         __HIP_MEMORY_SCOPE_AGENT) < target)
                    __builtin_amdgcn_s_sleep(1);
            }
            __syncthreads();
            asm volatile("buffer_inv sc0\n\ts_waitcnt vmcnt(0)" ::: "memory");
        }
    }
}

// ---------- BN stats (XCD-aligned, bf16 feat) + edge CSR scan (block 0) ----------
__global__ __launch_bounds__(256) void bn_stats_scan(const unsigned short* __restrict__ feat,
                                                     const float* __restrict__ lin_w,
                                                     const float* __restrict__ lin_b,
                                                     float* __restrict__ stats,
                                                     const int* __restrict__ cnt,
                                                     int* __restrict__ off,
                                                     int* __restrict__ cur) {
    __shared__ float wls[KF * C];
    __shared__ float red[4][2][C];
    __shared__ int ss[256];
    int t = threadIdx.x;
    if (blockIdx.x < 8) {                 // ---- edge_scan (block 0 only) ----
        if (blockIdx.x == 0) {
            int base = t * 32;
            int local[32];
            int s = 0;
            #pragma unroll
            for (int i = 0; i < 32; i++) { local[i] = cnt[base + i]; s += local[i]; }
            ss[t] = s;
            __syncthreads();
            #pragma unroll
            for (int d = 1; d < 256; d <<= 1) {
                int v = (t >= d) ? ss[t - d] : 0;
                __syncthreads();
                ss[t] += v;
                __syncthreads();
            }
            int excl = ss[t] - s;
            #pragma unroll
            for (int i = 0; i < 32; i++) { off[base + i] = excl; cur[base + i] = excl; excl += local[i]; }
        }
        return;
    }
    int blk = blockIdx.x - 8;             // ---- bn_stats ----
    wls[t] = lin_w[t];
    __syncthreads();
    int b = blk & 7;
    int i = (blk >> 3) * 256 + t;          // group of 4 elems, 32768/batch
    const uint2* fb = (const uint2*)(feat + (size_t)b * KF * NM);

    float4 hacc[C];
    #pragma unroll
    for (int c = 0; c < C; c++) {
        float bb = lin_b[c];
        hacc[c] = make_float4(bb, bb, bb, bb);
    }
    for (int kk = 0; kk < KF; kk++) {
        U2 u; u.v = fb[(size_t)kk * (NM / 4) + i];
        float p0 = bf2f(u.s[0]), p1 = bf2f(u.s[1]), p2 = bf2f(u.s[2]), p3 = bf2f(u.s[3]);
        #pragma unroll
        for (int c = 0; c < C; c++) {
            float wv = wls[kk * C + c];
            hacc[c].x = fmaf(p0, wv, hacc[c].x);
            hacc[c].y = fmaf(p1, wv, hacc[c].y);
            hacc[c].z = fmaf(p2, wv, hacc[c].z);
            hacc[c].w = fmaf(p3, wv, hacc[c].w);
        }
    }
    float s[C], ssq[C];
    #pragma unroll
    for (int c = 0; c < C; c++) {
        float4 hh = hacc[c];
        s[c] = hh.x + hh.y + hh.z + hh.w;
        ssq[c] = hh.x * hh.x + hh.y * hh.y + hh.z * hh.z + hh.w * hh.w;
    }
    #pragma unroll
    for (int o = 32; o > 0; o >>= 1)
        #pragma unroll
        for (int c = 0; c < C; c++) {
            s[c] += __shfl_down(s[c], o);
            ssq[c] += __shfl_down(ssq[c], o);
        }
    if ((t & 63) == 0) {
        int wv = t >> 6;
        #pragma unroll
        for (int c = 0; c < C; c++) { red[wv][0][c] = s[c]; red[wv][1][c] = ssq[c]; }
    }
    __syncthreads();
    if (t < 32) {
        int which = t >> 4, c = t & 15;
        float v = red[0][which][c] + red[1][which][c] + red[2][which][c] + red[3][which][c];
        atomicAdd(&stats[b * 32 + which * 16 + c], v);
    }
}

// ---------- BN apply + relu + mean over M -> x | edge fill (blocks >= 256) ----------
__global__ __launch_bounds__(256) void bnx_fill(const unsigned short* __restrict__ feat,
                                                const float* __restrict__ lin_w,
                                                const float* __restrict__ lin_b,
                                                const float* __restrict__ gam,
                                                const float* __restrict__ bet,
                                                const float* __restrict__ stats,
                                                float* __restrict__ x,
                                                const int* __restrict__ ei,
                                                int* __restrict__ cur,
                                                int* __restrict__ bucket) {
    __shared__ float wls[KF * C];
    __shared__ float red[8][32 * 17];
    int t = threadIdx.x;
    if (blockIdx.x >= 256) {              // ---- edge_fill ----
        int e = (blockIdx.x - 256) * 256 + t;
        bool is64 = (ei[1] == 0 && ei[3] == 0 && ei[5] == 0 && ei[7] == 0);
        int src, dst;
        if (is64) { src = ei[2 * e]; dst = ei[2 * (NE + e)]; }
        else      { src = ei[e];     dst = ei[NE + e]; }
        int pos = atomicAdd(&cur[dst], 1);
        bucket[pos] = src;
        return;
    }
    // ---- bn_x ----
    wls[t] = lin_w[t];
    __syncthreads();
    int grp = blockIdx.x;
    int b = grp & 7, n0 = (grp >> 3) * 32;
    int nl = t & 31, mg = t >> 5;
    int n = n0 + nl;

    const float inv_nm = 1.0f / (float)NM;
    float sc[C], sh[C], bb[C];
    #pragma unroll
    for (int c = 0; c < C; c++) {
        float mean = stats[b * 32 + c] * inv_nm;
        float var = stats[b * 32 + 16 + c] * inv_nm - mean * mean;
        sc[c] = gam[c] * rsqrtf(var + BN_EPS);
        sh[c] = bet[c] - mean * sc[c];
        bb[c] = lin_b[c];
    }
    const unsigned short* fb = feat + (size_t)b * KF * NM + n;
    float y[C] = {};
    for (int m = mg * 16; m < mg * 16 + 16; m++) {
        float p[KF];
        #pragma unroll
        for (int kk = 0; kk < KF; kk++) p[kk] = bf2f(fb[(size_t)kk * NM + (size_t)m * N]);
        #pragma unroll
        for (int c = 0; c < C; c++) {
            float hh = bb[c];
            #pragma unroll
            for (int kk = 0; kk < KF; kk++) hh = fmaf(p[kk], wls[kk * C + c], hh);
            y[c] += fmaxf(fmaf(hh, sc[c], sh[c]), 0.0f);
        }
    }
    #pragma unroll
    for (int c = 0; c < C; c++) red[mg][nl * 17 + c] = y[c];
    __syncthreads();
    #pragma unroll
    for (int q = 0; q < 2; q++) {
        int slot = t + q * 256;
        int snl = slot >> 4, c = slot & 15;
        float v = 0.0f;
        #pragma unroll
        for (int m8 = 0; m8 < 8; m8++) v += red[m8][snl * 17 + c];
        v *= (1.0f / (float)M);
        x[((size_t)b * N + n0 + snl) * C + c] = v;
    }
}

// ---------- fused gather + phi1 + phi2 ----------
__global__ __launch_bounds__(256) void phi_fused(const int* __restrict__ cnt,
                                                 const int* __restrict__ off,
                                                 const int* __restrict__ bucket,
                                                 const float* __restrict__ x,
                                                 const float* __restrict__ w1,
                                                 const float* __restrict__ b1,
                                                 const float* __restrict__ w2,
                                                 const float* __restrict__ b2,
                                                 float* __restrict__ out) {
    __shared__ float w1s[C * DPE];
    __shared__ float w2s[DPE * DPE];
    __shared__ float b2s[DPE];
    __shared__ float gsh[16][17];
    __shared__ float h1sh[16][DPE];
    int t = threadIdx.x;
    #pragma unroll
    for (int q = 0; q < 4; q++) w1s[t + q * 256] = w1[t + q * 256];
    #pragma unroll
    for (int q = 0; q < 16; q++) w2s[t + q * 256] = w2[t + q * 256];
    if (t < DPE) b2s[t] = b2[t];

    {   // gather: node nl, channel c
        int nl = t >> 4, c = t & 15;
        int n = blockIdx.x * 16 + nl;
        int o = off[n], d = cnt[n];
        float v = x[(size_t)n * C + c];
        int j = 0;
        for (; j + 4 <= d; j += 4) {
            int s0 = bucket[o + j], s1 = bucket[o + j + 1];
            int s2 = bucket[o + j + 2], s3 = bucket[o + j + 3];
            v += x[(size_t)s0 * C + c];
            v += x[(size_t)s1 * C + c];
            v += x[(size_t)s2 * C + c];
            v += x[(size_t)s3 * C + c];
        }
        for (; j < d; j++) v += x[(size_t)bucket[o + j] * C + c];
        gsh[nl][c] = v;
    }
    __syncthreads();
    #pragma unroll
    for (int q = 0; q < 4; q++) {       // phi1: 16 nodes x 64
        int item = t + 256 * q;
        int node = item >> 6, j = item & 63;
        float h = b1[j];
        #pragma unroll
        for (int c = 0; c < C; c++) h = fmaf(gsh[node][c], w1s[c * DPE + j], h);
        h1sh[node][j] = fmaxf(h, 0.0f);
    }
    __syncthreads();
    #pragma unroll
    for (int q = 0; q < 4; q++) {       // phi2: 16 nodes x 64
        int item = t + 256 * q;
        int node = item >> 6, d = item & 63;
        float o2 = b2s[d];
        #pragma unroll
        for (int j = 0; j < DPE; j++) o2 = fmaf(h1sh[node][j], w2s[j * DPE + d], o2);
        out[((size_t)blockIdx.x * 16 + node) * DPE + d] = o2;
    }
}

extern "C" void kernel_launch(void* const* d_in, const int* in_sizes, int n_in,
                              void* d_out, int out_size, void* d_ws, size_t ws_size,
                              hipStream_t stream) {
    const float* Lap   = (const float*)d_in[0];
    const float* W     = (const float*)d_in[1];
    const float* lin_w = (const float*)d_in[2];
    const float* lin_b = (const float*)d_in[3];
    const float* gam   = (const float*)d_in[4];
    const float* bet   = (const float*)d_in[5];
    const float* w1    = (const float*)d_in[6];
    const float* b1    = (const float*)d_in[7];
    const float* w2    = (const float*)d_in[8];
    const float* b2    = (const float*)d_in[9];
    const int*   ei    = (const int*)d_in[10];

    char* wsb = (char*)d_ws;
    unsigned short* feat = (unsigned short*)wsb;             // 32 MB (bf16)
    uint4* Pf    = (uint4*)(wsb + ((size_t)32 << 20));       // 8 MB (2 buffers)
    char* tail   = wsb + ((size_t)40 << 20);
    float* stats = (float*)tail;                             // 1 KB
    unsigned* bar = (unsigned*)(tail + 1024);                // k-loop [0..255], init [256..511]
    int* cnt     = (int*)(tail + 8192);                      // NV ints (32 KB)
    float* x     = (float*)(tail + 40960);
    int* off     = (int*)(x + (size_t)NV * C);
    int* cur     = off + NV;
    int* bucket  = cur + NV;                                 // NE ints
    float* out   = (float*)d_out;

    // allow 146 KB dynamic LDS; idempotent host-side call
    static bool attr_set = false;
    if (!attr_set) {
        hipFuncSetAttribute((const void*)gemm_chain,
                            hipFuncAttributeMaxDynamicSharedMemorySize, 149504);
        attr_set = true;
    }

    // one memset covers stats + bar + cnt (contiguous 40 KB)
    hipMemsetAsync(tail, 0, 40960, stream);
    gemm_chain<<<dim3(256), 512, 149504, stream>>>(Lap, W, ei, Pf, Pf + PFBUF,
                                                   feat, bar, cnt);
    bn_stats_scan<<<dim3(1032), 256, 0, stream>>>(feat, lin_w, lin_b, stats, cnt, off, cur);
    bnx_fill<<<dim3(768), 256, 0, stream>>>(feat, lin_w, lin_b, gam, bet, stats, x, ei, cur, bucket);
    phi_fused<<<dim3(NV / 16), 256, 0, stream>>>(cnt, off, bucket, x, w1, b1, w2, b2, out);
}